// Round 7
// baseline (82.775 us; speedup 1.0000x reference)
//
#include <hip/hip_runtime.h>
#include <stdint.h>

typedef uint16_t u16;
typedef __attribute__((ext_vector_type(4))) float f32x4;
typedef __attribute__((ext_vector_type(8))) short short8;
typedef __attribute__((ext_vector_type(4))) float float4v;
typedef __attribute__((ext_vector_type(4))) uint16_t u16x4;

#define DIMQ 1024
#define BATCH 8192
#define KDIM 1024
#define NDIM 1024
#define NBUILD 256    /* build blocks: 4 states each */
#define NNORM 512     /* norm blocks: 16 rows each */

#define RDL(v, l) __int_as_float(__builtin_amdgcn_readlane(__float_as_int(v), (l)))

__device__ __forceinline__ u16 f2bf(float f) {
  uint32_t u = __float_as_uint(f);
  u += 0x7fffu + ((u >> 16) & 1u);
  return (u16)(u >> 16);
}

// cross-lane xor exchange; DPP (VALU pipe) for masks 1,2,8; ds_swizzle for 4,16;
// bpermute-based __shfl_xor only for 32.  (verified R4)
template<int MASK>
__device__ __forceinline__ float lane_xor(float x) {
  if constexpr (MASK == 1)
    return __int_as_float(__builtin_amdgcn_update_dpp(0, __float_as_int(x), 0xB1, 0xF, 0xF, true));
  else if constexpr (MASK == 2)
    return __int_as_float(__builtin_amdgcn_update_dpp(0, __float_as_int(x), 0x4E, 0xF, 0xF, true));
  else if constexpr (MASK == 8)
    return __int_as_float(__builtin_amdgcn_update_dpp(0, __float_as_int(x), 0x128, 0xF, 0xF, true));
  else if constexpr (MASK == 4)
    return __int_as_float(__builtin_amdgcn_ds_swizzle(__float_as_int(x), 0x101F));
  else if constexpr (MASK == 16)
    return __int_as_float(__builtin_amdgcn_ds_swizzle(__float_as_int(x), 0x401F));
  else
    return __shfl_xor(x, 32, 64);
}

// one cross-lane gate applied to 16 regs (4 states x 4 amps): batched partner
// fetch (one 32-op burst -> single wait), then FMAs.  (verified R3/R4)
template<int MASK>
__device__ __forceinline__ void lane_gate16(float* ar, float* ai, int lane,
    float u00r, float u00i, float u01r, float u01i,
    float u10r, float u10i, float u11r, float u11i) {
  bool hi = (lane & MASK) != 0;
  float cmr = hi ? u11r : u00r, cmi = hi ? u11i : u00i;
  float cor = hi ? u10r : u01r, coi = hi ? u10i : u01i;
  float otr[16], oti[16];
#pragma unroll
  for (int r = 0; r < 16; ++r) otr[r] = lane_xor<MASK>(ar[r]);
#pragma unroll
  for (int r = 0; r < 16; ++r) oti[r] = lane_xor<MASK>(ai[r]);
#pragma unroll
  for (int r = 0; r < 16; ++r) {
    float nr = cmr*ar[r] - cmi*ai[r] + cor*otr[r] - coi*oti[r];
    float ni = cmr*ai[r] + cmi*ar[r] + cor*oti[r] + coi*otr[r];
    ar[r] = nr; ai[r] = ni;
  }
}

// in-register 2x2 butterfly on one amp pair
__device__ __forceinline__ void bfly(float &a0r, float &a0i, float &a1r, float &a1i,
    float u00r, float u00i, float u01r, float u01i,
    float u10r, float u10i, float u11r, float u11i) {
  float t0r = u00r*a0r - u00i*a0i + u01r*a1r - u01i*a1i;
  float t0i = u00r*a0i + u00i*a0r + u01r*a1i + u01i*a1r;
  float t1r = u10r*a0r - u10i*a0i + u11r*a1r - u11i*a1i;
  float t1i = u10r*a0i + u10i*a0r + u11r*a1i + u11i*a1r;
  a0r=t0r; a0i=t0i; a1r=t1r; a1i=t1i;
}

// complex 2x2 layout: {00r,00i, 01r,01i, 10r,10i, 11r,11i}
__device__ inline void cmul2x2(float* O, const float* A, const float* B) {
  for (int r = 0; r < 2; ++r)
    for (int c = 0; c < 2; ++c) {
      float re = 0.f, im = 0.f;
      for (int j = 0; j < 2; ++j) {
        float ar = A[(r*2+j)*2], ai = A[(r*2+j)*2+1];
        float br = B[(j*2+c)*2], bi = B[(j*2+c)*2+1];
        re += ar*br - ai*bi;
        im += ar*bi + ai*br;
      }
      O[(r*2+c)*2]   = re;
      O[(r*2+c)*2+1] = im;
    }
}
__device__ inline void mk_rx(float* m, float t) {
  float s, c; sincosf(0.5f*t, &s, &c);
  m[0]=c; m[1]=0; m[2]=0; m[3]=-s; m[4]=0; m[5]=-s; m[6]=c; m[7]=0;
}
__device__ inline void mk_ry(float* m, float t) {
  float s, c; sincosf(0.5f*t, &s, &c);
  m[0]=c; m[1]=0; m[2]=-s; m[3]=0; m[4]=s; m[5]=0; m[6]=c; m[7]=0;
}
__device__ inline void mk_rz(float* m, float t) {
  float s, c; sincosf(0.5f*t, &s, &c);
  m[0]=c; m[1]=-s; m[2]=0; m[3]=0; m[4]=0; m[5]=0; m[6]=c; m[7]=s;
}

// padded float2 index: +1 slot per 4 amps (write bases 5*tid contiguous,
// read banks spread)
__device__ __forceinline__ int pidx2(int y) { return y + (y >> 2); }

// Fused front kernel.
//   blocks [0, NBUILD):           build — block b builds states 4b..4b+3.
//     thread owns 16 regs: (state s, amp 4*tid+r) at flat index s*4+r.
//     amp bits: [1:0]=reg (bfly), [7:2]=lane (lane_gate16), [9:8]=wave (K+sigma
//     LDS round trip, verified R6).
//   blocks [NBUILD, NBUILD+NNORM): row-normalize x -> bf16, 16 rows/block
//     (4 sequential rows per wave).
__global__ __launch_bounds__(256, 4) void fused_front(const float* __restrict__ x,
                                                      const float* __restrict__ w,
                                                      u16* __restrict__ Abf,
                                                      u16* __restrict__ Bmat) {
  const int bid = blockIdx.x;
  const int tid = threadIdx.x;
  const int lane = tid & 63, wv = tid >> 6;

  __shared__ float2 sm[4][1280];   // 4 states x padded 1024 complex = 40 KB

  if (bid >= NBUILD) {
    // ---- normalize path: 4 rows per wave, sequential ----
    int base = (bid - NBUILD) * 16 + wv * 4;
#pragma unroll
    for (int it = 0; it < 4; ++it) {
      int row = base + it;
      const float* xr = x + (size_t)row * DIMQ;
      float4v v[4];
      float ss = 0.f;
#pragma unroll
      for (int j = 0; j < 4; ++j) {
        v[j] = *(const float4v*)(xr + j*256 + lane*4);
        ss += v[j][0]*v[j][0] + v[j][1]*v[j][1] + v[j][2]*v[j][2] + v[j][3]*v[j][3];
      }
#pragma unroll
      for (int off = 32; off; off >>= 1) ss += __shfl_xor(ss, off, 64);
      float inv = 1.0f / fmaxf(sqrtf(ss), 1e-12f);
      u16* orow = Abf + (size_t)row * DIMQ;
#pragma unroll
      for (int j = 0; j < 4; ++j) {
        u16x4 o;
#pragma unroll
        for (int e = 0; e < 4; ++e) o[e] = f2bf(v[j][e] * inv);
        *(u16x4*)(orow + j*256 + lane*4) = o;
      }
    }
    return;
  }

  // ---- build path ----
  // per-wave: lanes 0..49 compute the 50 fused adjoint gate matrices (R5/R6)
  float O0, O1, O2, O3, O4, O5, O6, O7;
  {
    float A[8], B[8], C[8], T8[8], O[8];
    int t = lane;
    if (t < 50) {
      if (t < 10) {
        mk_ry(A, -w[120 + t]);
        mk_rz(B, -w[130 + t]);
        mk_ry(C, -w[140 + t]);
      } else {
        int s = (t - 10) / 10, q = (t - 10) % 10, l = 3 - s;
        mk_rx(A, -w[l*30 + q]);
        mk_ry(B, -w[l*30 + 10 + q]);
        mk_rz(C, -w[l*30 + 20 + q]);
      }
      cmul2x2(T8, A, B);
      cmul2x2(O, T8, C);
    } else {
#pragma unroll
      for (int j = 0; j < 8; ++j) O[j] = 0.f;
    }
    O0=O[0]; O1=O[1]; O2=O[2]; O3=O[3]; O4=O[4]; O5=O[5]; O6=O[6]; O7=O[7];
  }

  // sigma (adjoint CNOT-ring perm) — GF(2)-linear decomposition (verified R6):
  // sigma(xb ^ r ^ (t<<8)) = sigma(xb) ^ S[r] ^ SW[t]
  const int xb = tid * 4;
  int yb = xb;
#pragma unroll
  for (int qq = 0; qq < 9; ++qq) yb ^= ((yb >> (9 - qq)) & 1) << (8 - qq);
  yb ^= (yb & 1) << 9;
  const int S[4]  = {0, 513, 515, 2};      // sigma(0..3)
  const int SW[4] = {0, 1023, 511, 512};   // sigma((0..3)<<8)

  int idx[4][4];   // [r][w], padded float2 units — stage-0 (identity) first
#pragma unroll
  for (int r = 0; r < 4; ++r)
#pragma unroll
    for (int wq = 0; wq < 4; ++wq)
      idx[r][wq] = pidx2(xb ^ r ^ ((wv ^ wq) << 8));
  const int wbase = 5 * tid;

  float ar[16], ai[16];
#pragma unroll
  for (int s = 0; s < 4; ++s)
#pragma unroll
    for (int r = 0; r < 4; ++r) {
      ar[s*4 + r] = ((xb + r) == (bid*4 + s)) ? 1.0f : 0.0f;
      ai[s*4 + r] = 0.0f;
    }

#pragma clang loop unroll(disable)
  for (int stage = 0; stage < 5; ++stage) {
    const int gbase = stage * 10;
    // ---- K (amp bits 9,8 gates) + perm via LDS round trip, per state ----
#pragma unroll
    for (int s = 0; s < 4; ++s)
#pragma unroll
      for (int r = 0; r < 4; ++r)
        sm[s][wbase + r] = (float2){ar[s*4 + r], ai[s*4 + r]};
    __syncthreads();
    {
      int g0 = gbase, g1 = gbase + 1;
      float U00r=RDL(O0,g0),U00i=RDL(O1,g0),U01r=RDL(O2,g0),U01i=RDL(O3,g0);
      float U10r=RDL(O4,g0),U10i=RDL(O5,g0),U11r=RDL(O6,g0),U11i=RDL(O7,g0);
      float V00r=RDL(O0,g1),V00i=RDL(O1,g1),V01r=RDL(O2,g1),V01i=RDL(O3,g1);
      float V10r=RDL(O4,g1),V10i=RDL(O5,g1),V11r=RDL(O6,g1),V11i=RDL(O7,g1);
      bool w1 = (wv & 2) != 0, w0 = (wv & 1) != 0;
      float uar = w1 ? U10r : U00r, uai = w1 ? U10i : U00i;   // U[W>>1][0]
      float ubr = w1 ? U11r : U01r, ubi = w1 ? U11i : U01i;   // U[W>>1][1]
      float var_ = w0 ? V10r : V00r, vai = w0 ? V10i : V00i;  // V[W&1][0]
      float vbr = w0 ? V11r : V01r, vbi = w0 ? V11i : V01i;   // V[W&1][1]
      float Kr[4], Ki[4];   // K[w] = U[W>>1][w>>1] * V[W&1][w&1]
      Kr[0] = uar*var_ - uai*vai; Ki[0] = uar*vai + uai*var_;
      Kr[1] = uar*vbr - uai*vbi;  Ki[1] = uar*vbi + uai*vbr;
      Kr[2] = ubr*var_ - ubi*vai; Ki[2] = ubr*vai + ubi*var_;
      Kr[3] = ubr*vbr - ubi*vbi;  Ki[3] = ubr*vbi + ubi*vbr;
#pragma unroll
      for (int s = 0; s < 4; ++s) {
        float2 v[4][4];
#pragma unroll
        for (int r = 0; r < 4; ++r)
#pragma unroll
          for (int wq = 0; wq < 4; ++wq) v[r][wq] = sm[s][idx[r][wq]];
#pragma unroll
        for (int r = 0; r < 4; ++r) {
          float nr = 0.f, ni = 0.f;
#pragma unroll
          for (int wq = 0; wq < 4; ++wq) {
            nr += Kr[wq]*v[r][wq].x - Ki[wq]*v[r][wq].y;
            ni += Kr[wq]*v[r][wq].y + Ki[wq]*v[r][wq].x;
          }
          ar[s*4 + r] = nr; ai[s*4 + r] = ni;
        }
      }
    }
    __syncthreads();
    // after stage 0, switch indices to the permuted map
    if (stage == 0) {
#pragma unroll
      for (int r = 0; r < 4; ++r)
#pragma unroll
        for (int wq = 0; wq < 4; ++wq)
          idx[r][wq] = pidx2(yb ^ S[r] ^ SW[wv ^ wq]);
    }
    // ---- lane gates: amp bits 7..2 -> lane masks 32..1 ----
    { int g = gbase + 2; lane_gate16<32>(ar, ai, lane, RDL(O0,g),RDL(O1,g),RDL(O2,g),RDL(O3,g),RDL(O4,g),RDL(O5,g),RDL(O6,g),RDL(O7,g)); }
    { int g = gbase + 3; lane_gate16<16>(ar, ai, lane, RDL(O0,g),RDL(O1,g),RDL(O2,g),RDL(O3,g),RDL(O4,g),RDL(O5,g),RDL(O6,g),RDL(O7,g)); }
    { int g = gbase + 4; lane_gate16< 8>(ar, ai, lane, RDL(O0,g),RDL(O1,g),RDL(O2,g),RDL(O3,g),RDL(O4,g),RDL(O5,g),RDL(O6,g),RDL(O7,g)); }
    { int g = gbase + 5; lane_gate16< 4>(ar, ai, lane, RDL(O0,g),RDL(O1,g),RDL(O2,g),RDL(O3,g),RDL(O4,g),RDL(O5,g),RDL(O6,g),RDL(O7,g)); }
    { int g = gbase + 6; lane_gate16< 2>(ar, ai, lane, RDL(O0,g),RDL(O1,g),RDL(O2,g),RDL(O3,g),RDL(O4,g),RDL(O5,g),RDL(O6,g),RDL(O7,g)); }
    { int g = gbase + 7; lane_gate16< 1>(ar, ai, lane, RDL(O0,g),RDL(O1,g),RDL(O2,g),RDL(O3,g),RDL(O4,g),RDL(O5,g),RDL(O6,g),RDL(O7,g)); }
    // ---- in-register gates: amp bits 1,0 ----
    { int g = gbase + 8;
      float u00r=RDL(O0,g),u00i=RDL(O1,g),u01r=RDL(O2,g),u01i=RDL(O3,g);
      float u10r=RDL(O4,g),u10i=RDL(O5,g),u11r=RDL(O6,g),u11i=RDL(O7,g);
#pragma unroll
      for (int s = 0; s < 4; ++s) {
        bfly(ar[s*4+0],ai[s*4+0],ar[s*4+2],ai[s*4+2], u00r,u00i,u01r,u01i,u10r,u10i,u11r,u11i);
        bfly(ar[s*4+1],ai[s*4+1],ar[s*4+3],ai[s*4+3], u00r,u00i,u01r,u01i,u10r,u10i,u11r,u11i);
      }
    }
    { int g = gbase + 9;
      float u00r=RDL(O0,g),u00i=RDL(O1,g),u01r=RDL(O2,g),u01i=RDL(O3,g);
      float u10r=RDL(O4,g),u10i=RDL(O5,g),u11r=RDL(O6,g),u11i=RDL(O7,g);
#pragma unroll
      for (int s = 0; s < 4; ++s) {
        bfly(ar[s*4+0],ai[s*4+0],ar[s*4+1],ai[s*4+1], u00r,u00i,u01r,u01i,u10r,u10i,u11r,u11i);
        bfly(ar[s*4+2],ai[s*4+2],ar[s*4+3],ai[s*4+3], u00r,u00i,u01r,u01i,u10r,u10i,u11r,u11i);
      }
    }
  }

  // write rows 4*bid..4*bid+3 of M = Re(U) as bf16 (8B/thread/state, coalesced)
#pragma unroll
  for (int s = 0; s < 4; ++s) {
    u16x4 o;
#pragma unroll
    for (int r = 0; r < 4; ++r) o[r] = f2bf(ar[s*4 + r]);
    *(u16x4*)(Bmat + (size_t)(bid*4 + s) * DIMQ + xb) = o;
  }
}

// C[8192,1024] = A[8192,1024] * B[1024,1024]^T   (bf16 in, fp32 out)
// 128x128 tile, BK=32, 4 waves (2x2 of 64x64), 16x16x32 bf16 MFMA,
// global_load_lds width-16 staging (m97 structure).
__global__ __launch_bounds__(256) void gemm_bt(const u16* __restrict__ A,
                                               const u16* __restrict__ Bm,
                                               float* __restrict__ C) {
  __shared__ u16 As[128*32];
  __shared__ u16 Bs[128*32];
  int t = threadIdx.x, lane = t & 63, wave = t >> 6;
  int bid = blockIdx.x;
  int nid = ((bid & 7) << 6) | (bid >> 3);
  int bm = nid >> 3, bn = nid & 7;
  size_t aBase = (size_t)bm * 128 * KDIM;
  size_t bBase = (size_t)bn * 128 * KDIM;
  int r0 = wave*16 + (lane >> 2);
  int c0 = (lane & 3) * 8;
  int wm = (wave >> 1) * 64, wn = (wave & 1) * 64;
  int la = lane & 15, lk = (lane >> 4) * 8;
  f32x4 acc[4][4];
#pragma unroll
  for (int m = 0; m < 4; ++m)
#pragma unroll
    for (int n = 0; n < 4; ++n) acc[m][n] = (f32x4){0.f, 0.f, 0.f, 0.f};

  for (int k0 = 0; k0 < KDIM; k0 += 32) {
    __syncthreads();
#pragma unroll
    for (int j = 0; j < 2; ++j) {
      __builtin_amdgcn_global_load_lds(
          (const __attribute__((address_space(1))) void*)(A + aBase + (size_t)(j*64 + r0)*KDIM + k0 + c0),
          (__attribute__((address_space(3))) void*)((char*)As + j*4096 + wave*1024), 16, 0, 0);
      __builtin_amdgcn_global_load_lds(
          (const __attribute__((address_space(1))) void*)(Bm + bBase + (size_t)(j*64 + r0)*KDIM + k0 + c0),
          (__attribute__((address_space(3))) void*)((char*)Bs + j*4096 + wave*1024), 16, 0, 0);
    }
    __syncthreads();
    short8 af[4], bf[4];
#pragma unroll
    for (int m = 0; m < 4; ++m) af[m] = *(const short8*)&As[(wm + m*16 + la)*32 + lk];
#pragma unroll
    for (int n = 0; n < 4; ++n) bf[n] = *(const short8*)&Bs[(wn + n*16 + la)*32 + lk];
#pragma unroll
    for (int m = 0; m < 4; ++m)
#pragma unroll
      for (int n = 0; n < 4; ++n)
        acc[m][n] = __builtin_amdgcn_mfma_f32_16x16x32_bf16(af[m], bf[n], acc[m][n], 0, 0, 0);
  }

  int orow0 = bm*128 + wm + (lane >> 4)*4;
  int ocol0 = bn*128 + wn + la;
#pragma unroll
  for (int m = 0; m < 4; ++m)
#pragma unroll
    for (int n = 0; n < 4; ++n)
#pragma unroll
      for (int j = 0; j < 4; ++j)
        C[(size_t)(orow0 + m*16 + j)*NDIM + ocol0 + n*16] = acc[m][n][j];
}

extern "C" void kernel_launch(void* const* d_in, const int* in_sizes, int n_in,
                              void* d_out, int out_size, void* d_ws, size_t ws_size,
                              hipStream_t stream) {
  const float* x = (const float*)d_in[0];
  const float* w = (const float*)d_in[1];
  float* out = (float*)d_out;
  char* ws = (char*)d_ws;
  u16* Bmat = (u16*)(ws + 4096);                             // 2 MB
  u16* Abf  = (u16*)(ws + 4096 + 2*1024*1024);               // 16 MB

  fused_front<<<NBUILD + NNORM, 256, 0, stream>>>(x, w, Abf, Bmat);
  gemm_bt<<<(BATCH/128)*(NDIM/128), 256, 0, stream>>>(Abf, Bmat, out);
}